// Round 8
// baseline (689.213 us; speedup 1.0000x reference)
//
#include <hip/hip_runtime.h>

#define N_NODES 100000
#define N_EDGES 1200000
#define D 64

#define BIN_SHIFT 8
#define NODES_PER_BIN 256
#define NBINS ((N_NODES + NODES_PER_BIN - 1) / NODES_PER_BIN)   // 391
#define NBLK_A 256
#define CHUNK ((N_EDGES + NBLK_A - 1) / NBLK_A)                 // 4688

// ---- workspace layout (bytes), total ~22.8 MB ----
#define OFF_H    0u          // ushort[N_NODES*D]          12.8 MB (h in bf16)
#define OFF_CSR  12800000u   // int2[N_EDGES]               9.6 MB {src|dlow<<17, w_bits}
#define OFF_CNT  22400000u   // int[NBINS*NBLK_A]           counts -> offs (in place)
#define OFF_TOT  22800384u   // int[NBINS]                  per-bin totals
#define OFF_BASE 22801948u   // int[NBINS+1]                bin base offsets

__device__ __forceinline__ unsigned short f2bf(float f) {
    unsigned u = __float_as_uint(f);
    return (unsigned short)((u + 0x7FFFu + ((u >> 16) & 1u)) >> 16);  // RNE
}
__device__ __forceinline__ float bf2f(unsigned short s) {
    return __uint_as_float(((unsigned)s) << 16);
}

// ---------------------------------------------------------------------------
// h = bf16(x @ W^T + b). One wave per block, 16 nodes; lane = out feature.
// W row in 64 VGPRs; x reads wave-uniform (scalar path). No LDS.
// ---------------------------------------------------------------------------
__global__ __launch_bounds__(64) void linear_kernel(
    const float* __restrict__ x, const float* __restrict__ W,
    const float* __restrict__ b, unsigned short* __restrict__ h) {
    int lane = threadIdx.x;
    float4 wr[16];
#pragma unroll
    for (int j = 0; j < 16; ++j)
        wr[j] = *reinterpret_cast<const float4*>(&W[lane * D + j * 4]);
    float bias = b[lane];
    int base = blockIdx.x * 16;
    for (int c = 0; c < 16; ++c) {
        int node = base + c;  // wave-uniform
        const float4* xr = reinterpret_cast<const float4*>(&x[(size_t)node * D]);
        float a0 = bias, a1 = 0.0f, a2 = 0.0f, a3 = 0.0f;
#pragma unroll
        for (int j = 0; j < 16; j += 4) {
            float4 x0 = xr[j], x1 = xr[j + 1], x2 = xr[j + 2], x3 = xr[j + 3];
            a0 = fmaf(wr[j].x, x0.x, fmaf(wr[j].y, x0.y,
                 fmaf(wr[j].z, x0.z, fmaf(wr[j].w, x0.w, a0))));
            a1 = fmaf(wr[j+1].x, x1.x, fmaf(wr[j+1].y, x1.y,
                 fmaf(wr[j+1].z, x1.z, fmaf(wr[j+1].w, x1.w, a1))));
            a2 = fmaf(wr[j+2].x, x2.x, fmaf(wr[j+2].y, x2.y,
                 fmaf(wr[j+2].z, x2.z, fmaf(wr[j+2].w, x2.w, a2))));
            a3 = fmaf(wr[j+3].x, x3.x, fmaf(wr[j+3].y, x3.y,
                 fmaf(wr[j+3].z, x3.z, fmaf(wr[j+3].w, x3.w, a3))));
        }
        h[(size_t)node * D + lane] = f2bf((a0 + a1) + (a2 + a3));
    }
}

// ---------------------------------------------------------------------------
// Pass A1: per-(bin, block) edge counts via LDS histogram.
// ---------------------------------------------------------------------------
__global__ __launch_bounds__(256) void count_kernel(
    const int* __restrict__ dst, int* __restrict__ counts) {
    __shared__ int cnt[NBINS];
    int tid = threadIdx.x, blk = blockIdx.x;
    for (int i = tid; i < NBINS; i += 256) cnt[i] = 0;
    __syncthreads();
    int eend = min(N_EDGES, (blk + 1) * CHUNK);
    for (int e = blk * CHUNK + tid; e < eend; e += 256)
        atomicAdd(&cnt[dst[e] >> BIN_SHIFT], 1);
    __syncthreads();
    for (int i = tid; i < NBINS; i += 256)
        counts[i * NBLK_A + blk] = cnt[i];
}

// ---------------------------------------------------------------------------
// Pass A2: per-bin exclusive scan over blocks (one block per bin, in place).
// ---------------------------------------------------------------------------
__global__ __launch_bounds__(256) void rowscan_kernel(
    int* __restrict__ counts, int* __restrict__ bintot) {
    __shared__ int s[256];
    int bin = blockIdx.x, tid = threadIdx.x;
    int c = counts[bin * NBLK_A + tid];
    s[tid] = c; __syncthreads();
    for (int off = 1; off < 256; off <<= 1) {
        int v = (tid >= off) ? s[tid - off] : 0;
        __syncthreads(); s[tid] += v; __syncthreads();
    }
    counts[bin * NBLK_A + tid] = s[tid] - c;   // exclusive
    if (tid == 255) bintot[bin] = s[255];
}

// ---------------------------------------------------------------------------
// Pass A2b: exclusive scan over 391 bin totals -> binbase[0..NBINS].
// ---------------------------------------------------------------------------
__global__ __launch_bounds__(512) void basescan_kernel(
    const int* __restrict__ bintot, int* __restrict__ binbase) {
    __shared__ int s[512];
    int tid = threadIdx.x;
    int c = (tid < NBINS) ? bintot[tid] : 0;
    s[tid] = c; __syncthreads();
    for (int off = 1; off < 512; off <<= 1) {
        int v = (tid >= off) ? s[tid - off] : 0;
        __syncthreads(); s[tid] += v; __syncthreads();
    }
    int excl = s[tid] - c;
    if (tid < NBINS) binbase[tid] = excl;
    if (tid == NBINS - 1) binbase[NBINS] = excl + c;
}

// ---------------------------------------------------------------------------
// Pass A3: write edges into per-(bin, block) private CSR regions.
// Block's writes confined to its own ~37 KB -> full-line writebacks.
// ---------------------------------------------------------------------------
__global__ __launch_bounds__(256) void binfill_kernel(
    const int* __restrict__ src, const int* __restrict__ dst,
    const float* __restrict__ w, const int* __restrict__ counts,
    const int* __restrict__ binbase, int2* __restrict__ csr) {
    __shared__ int cur[NBINS];
    int tid = threadIdx.x, blk = blockIdx.x;
    for (int i = tid; i < NBINS; i += 256)
        cur[i] = binbase[i] + counts[i * NBLK_A + blk];
    __syncthreads();
    int eend = min(N_EDGES, (blk + 1) * CHUNK);
    for (int e = blk * CHUNK + tid; e < eend; e += 256) {
        int d = dst[e];
        int bin = d >> BIN_SHIFT;
        int slot = atomicAdd(&cur[bin], 1);
        csr[slot] = make_int2(src[e] | ((d & (NODES_PER_BIN - 1)) << 17),
                              __float_as_int(w[e]));
    }
}

// ---------------------------------------------------------------------------
// Pass B: one block per bin. 64 KB LDS fp32 accumulator (256 nodes x 64).
// Edges read sequentially; h rows coalesced; LDS atomic adds (2-way banks).
// Epilogue writes out (fully covers out -> no memset needed).
// ---------------------------------------------------------------------------
__global__ __launch_bounds__(256) void binacc_kernel(
    const unsigned short* __restrict__ h, const int* __restrict__ binbase,
    const int2* __restrict__ csr, float* __restrict__ out) {
    __shared__ float acc[NODES_PER_BIN * D];   // 64 KB
    int tid = threadIdx.x;
    int bin = blockIdx.x;
    float4* a4 = reinterpret_cast<float4*>(acc);
#pragma unroll
    for (int i = tid; i < NODES_PER_BIN * D / 4; i += 256)
        a4[i] = make_float4(0.f, 0.f, 0.f, 0.f);
    __syncthreads();

    int lane = tid & 63, wid = tid >> 6;
    int start = binbase[bin], endv = binbase[bin + 1];
    int cnt = endv - start;
    int per = (cnt + 3) >> 2;
    int i = start + wid * per;
    int iend = min(i + per, endv);

    for (; i + 4 <= iend; i += 4) {
        int2 p0 = csr[i], p1 = csr[i+1], p2 = csr[i+2], p3 = csr[i+3];
        float h0 = bf2f(h[(size_t)(p0.x & 0x1FFFF) * D + lane]);
        float h1 = bf2f(h[(size_t)(p1.x & 0x1FFFF) * D + lane]);
        float h2 = bf2f(h[(size_t)(p2.x & 0x1FFFF) * D + lane]);
        float h3 = bf2f(h[(size_t)(p3.x & 0x1FFFF) * D + lane]);
        atomicAdd(&acc[((p0.x >> 17) & 255) * D + lane], h0 * __int_as_float(p0.y));
        atomicAdd(&acc[((p1.x >> 17) & 255) * D + lane], h1 * __int_as_float(p1.y));
        atomicAdd(&acc[((p2.x >> 17) & 255) * D + lane], h2 * __int_as_float(p2.y));
        atomicAdd(&acc[((p3.x >> 17) & 255) * D + lane], h3 * __int_as_float(p3.y));
    }
    for (; i < iend; ++i) {
        int2 p = csr[i];
        float hv = bf2f(h[(size_t)(p.x & 0x1FFFF) * D + lane]);
        atomicAdd(&acc[((p.x >> 17) & 255) * D + lane], hv * __int_as_float(p.y));
    }
    __syncthreads();

    int node0 = bin << BIN_SHIFT;
    int lim = (min(NODES_PER_BIN, N_NODES - node0)) * (D / 4);
    float4* o4 = reinterpret_cast<float4*>(out + (size_t)node0 * D);
    for (int k = tid; k < lim; k += 256) o4[k] = a4[k];
}

extern "C" void kernel_launch(void* const* d_in, const int* in_sizes, int n_in,
                              void* d_out, int out_size, void* d_ws, size_t ws_size,
                              hipStream_t stream) {
    const float* x   = (const float*)d_in[0];
    const int*   src = (const int*)d_in[1];
    const int*   dst = (const int*)d_in[2];
    const float* w   = (const float*)d_in[3];
    const float* W   = (const float*)d_in[4];
    const float* b   = (const float*)d_in[5];
    float*       out = (float*)d_out;

    char* ws = (char*)d_ws;
    unsigned short* h       = (unsigned short*)(ws + OFF_H);
    int2*           csr     = (int2*)(ws + OFF_CSR);
    int*            counts  = (int*)(ws + OFF_CNT);
    int*            bintot  = (int*)(ws + OFF_TOT);
    int*            binbase = (int*)(ws + OFF_BASE);

    linear_kernel  <<<N_NODES / 16, 64, 0, stream>>>(x, W, b, h);
    count_kernel   <<<NBLK_A, 256, 0, stream>>>(dst, counts);
    rowscan_kernel <<<NBINS, 256, 0, stream>>>(counts, bintot);
    basescan_kernel<<<1, 512, 0, stream>>>(bintot, binbase);
    binfill_kernel <<<NBLK_A, 256, 0, stream>>>(src, dst, w, counts, binbase, csr);
    binacc_kernel  <<<NBINS, 256, 0, stream>>>(h, binbase, csr, out);
}

// Round 10
// 606.353 us; speedup vs baseline: 1.1367x; 1.1367x over previous
//
#include <hip/hip_runtime.h>

#define N_NODES 100000
#define N_EDGES 1200000
#define D 64

#define BIN_SHIFT 8
#define NODES_PER_BIN 256
#define NBINS ((N_NODES + NODES_PER_BIN - 1) / NODES_PER_BIN)   // 391
#define NBLK_A 256
#define CHUNK ((N_EDGES + NBLK_A - 1) / NBLK_A)                 // 4688

// ---- workspace layout (bytes), total ~22.8 MB ----
#define OFF_H    0u          // ushort[N_NODES*D]          12.8 MB (h in bf16)
#define OFF_CSR  12800000u   // int2[N_EDGES]               9.6 MB {src|dlow<<17, w_bits}
#define OFF_CNT  22400000u   // int[NBINS*NBLK_A]           counts -> offs (in place)
#define OFF_TOT  22800384u   // int[NBINS]                  per-bin totals
#define OFF_BASE 22801948u   // int[NBINS+1]                bin base offsets

__device__ __forceinline__ unsigned short f2bf(float f) {
    unsigned u = __float_as_uint(f);
    return (unsigned short)((u + 0x7FFFu + ((u >> 16) & 1u)) >> 16);  // RNE
}
__device__ __forceinline__ float bf2f(unsigned short s) {
    return __uint_as_float(((unsigned)s) << 16);
}

// ---------------------------------------------------------------------------
// h = bf16(x @ W^T + b), tiled: block = 64 nodes x 64 feats, 256 threads,
// each thread a 4x4 register tile. x and W staged TRANSPOSED in LDS with
// pad 68 -> conflict-free ds_read_b128 in the k-loop (2 reads + 16 FMA per k).
// LDS 34.8 KB -> 4 blocks/CU. Bounded by LDS read throughput (~12 us).
// ---------------------------------------------------------------------------
__global__ __launch_bounds__(256) void linear_kernel(
    const float* __restrict__ x, const float* __restrict__ W,
    const float* __restrict__ b, unsigned short* __restrict__ h) {
    __shared__ float xsT[D][68];  // xsT[k][node]
    __shared__ float WsT[D][68];  // WsT[k][feat]
    int t = threadIdx.x;
    int base = blockIdx.x * 64;
    int rr = t >> 4;           // 0..15
    int k0 = (t & 15) * 4;     // 0..60
#pragma unroll
    for (int p = 0; p < 4; ++p) {
        int o = rr + p * 16;
        float4 wv = *reinterpret_cast<const float4*>(&W[o * D + k0]);
        WsT[k0 + 0][o] = wv.x; WsT[k0 + 1][o] = wv.y;
        WsT[k0 + 2][o] = wv.z; WsT[k0 + 3][o] = wv.w;
        int node = base + o;
        float4 xv = (node < N_NODES)
            ? *reinterpret_cast<const float4*>(&x[(size_t)node * D + k0])
            : make_float4(0.f, 0.f, 0.f, 0.f);
        xsT[k0 + 0][o] = xv.x; xsT[k0 + 1][o] = xv.y;
        xsT[k0 + 2][o] = xv.z; xsT[k0 + 3][o] = xv.w;
    }
    __syncthreads();

    int nn = (t >> 4) * 4;     // node group 0..60
    int fo = (t & 15) * 4;     // feat group 0..60
    float4 bv = *reinterpret_cast<const float4*>(&b[fo]);
    float a[4][4];
#pragma unroll
    for (int ni = 0; ni < 4; ++ni) {
        a[ni][0] = bv.x; a[ni][1] = bv.y; a[ni][2] = bv.z; a[ni][3] = bv.w;
    }
#pragma unroll 8
    for (int k = 0; k < D; ++k) {
        float4 xv = *reinterpret_cast<const float4*>(&xsT[k][nn]);
        float4 wv = *reinterpret_cast<const float4*>(&WsT[k][fo]);
        a[0][0] = fmaf(xv.x, wv.x, a[0][0]); a[0][1] = fmaf(xv.x, wv.y, a[0][1]);
        a[0][2] = fmaf(xv.x, wv.z, a[0][2]); a[0][3] = fmaf(xv.x, wv.w, a[0][3]);
        a[1][0] = fmaf(xv.y, wv.x, a[1][0]); a[1][1] = fmaf(xv.y, wv.y, a[1][1]);
        a[1][2] = fmaf(xv.y, wv.z, a[1][2]); a[1][3] = fmaf(xv.y, wv.w, a[1][3]);
        a[2][0] = fmaf(xv.z, wv.x, a[2][0]); a[2][1] = fmaf(xv.z, wv.y, a[2][1]);
        a[2][2] = fmaf(xv.z, wv.z, a[2][2]); a[2][3] = fmaf(xv.z, wv.w, a[2][3]);
        a[3][0] = fmaf(xv.w, wv.x, a[3][0]); a[3][1] = fmaf(xv.w, wv.y, a[3][1]);
        a[3][2] = fmaf(xv.w, wv.z, a[3][2]); a[3][3] = fmaf(xv.w, wv.w, a[3][3]);
    }
#pragma unroll
    for (int ni = 0; ni < 4; ++ni) {
        int node = base + nn + ni;
        if (node < N_NODES) {
            ushort4 hv;
            hv.x = f2bf(a[ni][0]); hv.y = f2bf(a[ni][1]);
            hv.z = f2bf(a[ni][2]); hv.w = f2bf(a[ni][3]);
            *reinterpret_cast<ushort4*>(&h[(size_t)node * D + fo]) = hv;
        }
    }
}

// ---------------------------------------------------------------------------
// Pass A1: per-(bin, block) edge counts via LDS histogram.
// ---------------------------------------------------------------------------
__global__ __launch_bounds__(256) void count_kernel(
    const int* __restrict__ dst, int* __restrict__ counts) {
    __shared__ int cnt[NBINS];
    int tid = threadIdx.x, blk = blockIdx.x;
    for (int i = tid; i < NBINS; i += 256) cnt[i] = 0;
    __syncthreads();
    int eend = min(N_EDGES, (blk + 1) * CHUNK);
    for (int e = blk * CHUNK + tid; e < eend; e += 256)
        atomicAdd(&cnt[dst[e] >> BIN_SHIFT], 1);
    __syncthreads();
    for (int i = tid; i < NBINS; i += 256)
        counts[i * NBLK_A + blk] = cnt[i];
}

// ---------------------------------------------------------------------------
// Pass A2: per-bin exclusive scan over blocks (one block per bin, in place).
// ---------------------------------------------------------------------------
__global__ __launch_bounds__(256) void rowscan_kernel(
    int* __restrict__ counts, int* __restrict__ bintot) {
    __shared__ int s[256];
    int bin = blockIdx.x, tid = threadIdx.x;
    int c = counts[bin * NBLK_A + tid];
    s[tid] = c; __syncthreads();
    for (int off = 1; off < 256; off <<= 1) {
        int v = (tid >= off) ? s[tid - off] : 0;
        __syncthreads(); s[tid] += v; __syncthreads();
    }
    counts[bin * NBLK_A + tid] = s[tid] - c;   // exclusive
    if (tid == 255) bintot[bin] = s[255];
}

// ---------------------------------------------------------------------------
// Pass A2b: exclusive scan over 391 bin totals -> binbase[0..NBINS].
// ---------------------------------------------------------------------------
__global__ __launch_bounds__(512) void basescan_kernel(
    const int* __restrict__ bintot, int* __restrict__ binbase) {
    __shared__ int s[512];
    int tid = threadIdx.x;
    int c = (tid < NBINS) ? bintot[tid] : 0;
    s[tid] = c; __syncthreads();
    for (int off = 1; off < 512; off <<= 1) {
        int v = (tid >= off) ? s[tid - off] : 0;
        __syncthreads(); s[tid] += v; __syncthreads();
    }
    int excl = s[tid] - c;
    if (tid < NBINS) binbase[tid] = excl;
    if (tid == NBINS - 1) binbase[NBINS] = excl + c;
}

// ---------------------------------------------------------------------------
// Pass A3: write edges into per-(bin, block) private CSR regions.
// Block's writes confined to its own regions -> near-full-line writebacks.
// ---------------------------------------------------------------------------
__global__ __launch_bounds__(256) void binfill_kernel(
    const int* __restrict__ src, const int* __restrict__ dst,
    const float* __restrict__ w, const int* __restrict__ counts,
    const int* __restrict__ binbase, int2* __restrict__ csr) {
    __shared__ int cur[NBINS];
    int tid = threadIdx.x, blk = blockIdx.x;
    for (int i = tid; i < NBINS; i += 256)
        cur[i] = binbase[i] + counts[i * NBLK_A + blk];
    __syncthreads();
    int eend = min(N_EDGES, (blk + 1) * CHUNK);
    for (int e = blk * CHUNK + tid; e < eend; e += 256) {
        int d = dst[e];
        int bin = d >> BIN_SHIFT;
        int slot = atomicAdd(&cur[bin], 1);
        csr[slot] = make_int2(src[e] | ((d & (NODES_PER_BIN - 1)) << 17),
                              __float_as_int(w[e]));
    }
}

// ---------------------------------------------------------------------------
// Pass B: 4 sub-blocks per bin (grid NBINS*4); sub-block sb owns the bin's
// 64-node quarter with a 16 KB LDS accumulator. All 4 waves scan the bin's
// full CSR range (contiguous quarter each, 4-entry batched broadcast loads);
// wave-uniform filter (dlow>>6)==sb selects this sub-block's edges.
// Occupancy: 1564 blocks, 16 KB LDS -> ~6 blocks/CU (vs 391 blocks/64 KB
// before, which measured 13% occupancy and 518 us pure latency).
// ---------------------------------------------------------------------------
__global__ __launch_bounds__(256) void binacc_kernel(
    const unsigned short* __restrict__ h, const int* __restrict__ binbase,
    const int2* __restrict__ csr, float* __restrict__ out) {
    __shared__ float acc[64 * D];   // 16 KB
    int tid = threadIdx.x;
    int bin = blockIdx.x >> 2;
    int sb  = blockIdx.x & 3;
    float4* a4 = reinterpret_cast<float4*>(acc);
#pragma unroll
    for (int i = tid; i < 64 * D / 4; i += 256)
        a4[i] = make_float4(0.f, 0.f, 0.f, 0.f);
    __syncthreads();

    int lane = tid & 63, wid = tid >> 6;
    int start = binbase[bin], endv = binbase[bin + 1];
    int cnt = endv - start;
    int per = (cnt + 3) >> 2;
    int i = start + wid * per;
    int iend = min(i + per, endv);

#define DO_EDGE(p)                                                          \
    {   int dl = ((p).x >> 17) & 255;                                       \
        if ((dl >> 6) == sb) {                                              \
            float hv = bf2f(h[(size_t)((p).x & 0x1FFFF) * D + lane]);       \
            atomicAdd(&acc[(dl & 63) * D + lane],                           \
                      hv * __int_as_float((p).y));                          \
        }                                                                   \
    }

    for (; i + 4 <= iend; i += 4) {
        int2 p0 = csr[i], p1 = csr[i + 1], p2 = csr[i + 2], p3 = csr[i + 3];
        DO_EDGE(p0) DO_EDGE(p1) DO_EDGE(p2) DO_EDGE(p3)
    }
    for (; i < iend; ++i) {
        int2 p = csr[i];
        DO_EDGE(p)
    }
#undef DO_EDGE
    __syncthreads();

    int node0 = (bin << BIN_SHIFT) + sb * 64;
    int lim = min(64, N_NODES - node0);
    if (lim > 0) {
        float4* o4 = reinterpret_cast<float4*>(out + (size_t)node0 * D);
        for (int k = tid; k < lim * (D / 4); k += 256) o4[k] = a4[k];
    }
}

extern "C" void kernel_launch(void* const* d_in, const int* in_sizes, int n_in,
                              void* d_out, int out_size, void* d_ws, size_t ws_size,
                              hipStream_t stream) {
    const float* x   = (const float*)d_in[0];
    const int*   src = (const int*)d_in[1];
    const int*   dst = (const int*)d_in[2];
    const float* w   = (const float*)d_in[3];
    const float* W   = (const float*)d_in[4];
    const float* b   = (const float*)d_in[5];
    float*       out = (float*)d_out;

    char* ws = (char*)d_ws;
    unsigned short* h       = (unsigned short*)(ws + OFF_H);
    int2*           csr     = (int2*)(ws + OFF_CSR);
    int*            counts  = (int*)(ws + OFF_CNT);
    int*            bintot  = (int*)(ws + OFF_TOT);
    int*            binbase = (int*)(ws + OFF_BASE);

    linear_kernel  <<<(N_NODES + 63) / 64, 256, 0, stream>>>(x, W, b, h);
    count_kernel   <<<NBLK_A, 256, 0, stream>>>(dst, counts);
    rowscan_kernel <<<NBINS, 256, 0, stream>>>(counts, bintot);
    basescan_kernel<<<1, 512, 0, stream>>>(bintot, binbase);
    binfill_kernel <<<NBLK_A, 256, 0, stream>>>(src, dst, w, counts, binbase, csr);
    binacc_kernel  <<<NBINS * 4, 256, 0, stream>>>(h, binbase, csr, out);
}

// Round 12
// 597.255 us; speedup vs baseline: 1.1540x; 1.0152x over previous
//
#include <hip/hip_runtime.h>

#define N_NODES 100000
#define N_EDGES 1200000
#define D 64

#define BIN_SHIFT 6
#define NODES_PER_BIN 64
#define NBINS ((N_NODES + NODES_PER_BIN - 1) / NODES_PER_BIN)   // 1563
#define NBLK_A 256
#define CHUNK ((N_EDGES + NBLK_A - 1) / NBLK_A)                 // 4688

// ---- workspace layout (bytes), total ~24.0 MB ----
#define OFF_H    0u          // ushort[N_NODES*D]          12.8 MB (h in bf16)
#define OFF_CSR  12800000u   // int2[N_EDGES]               9.6 MB {src|dlow<<17, w_bits}
#define OFF_CNT  22400000u   // int[NBINS*NBLK_A]           1.6 MB counts->offs
#define OFF_TOT  24001024u   // int[NBINS]
#define OFF_BASE 24007280u   // int[NBINS+1]

__device__ __forceinline__ unsigned short f2bf(float f) {
    unsigned u = __float_as_uint(f);
    return (unsigned short)((u + 0x7FFFu + ((u >> 16) & 1u)) >> 16);  // RNE
}
__device__ __forceinline__ float bf2f(unsigned short s) {
    return __uint_as_float(((unsigned)s) << 16);
}

// ---------------------------------------------------------------------------
// h = bf16(x @ W^T + b), tiled: block = 64 nodes x 64 feats, 256 threads,
// 4x4 register tile each; x/W staged transposed in padded LDS.
// ---------------------------------------------------------------------------
__global__ __launch_bounds__(256) void linear_kernel(
    const float* __restrict__ x, const float* __restrict__ W,
    const float* __restrict__ b, unsigned short* __restrict__ h) {
    __shared__ float xsT[D][68];  // xsT[k][node]
    __shared__ float WsT[D][68];  // WsT[k][feat]
    int t = threadIdx.x;
    int base = blockIdx.x * 64;
    int rr = t >> 4;           // 0..15
    int k0 = (t & 15) * 4;     // 0..60
#pragma unroll
    for (int p = 0; p < 4; ++p) {
        int o = rr + p * 16;
        float4 wv = *reinterpret_cast<const float4*>(&W[o * D + k0]);
        WsT[k0 + 0][o] = wv.x; WsT[k0 + 1][o] = wv.y;
        WsT[k0 + 2][o] = wv.z; WsT[k0 + 3][o] = wv.w;
        int node = base + o;
        float4 xv = (node < N_NODES)
            ? *reinterpret_cast<const float4*>(&x[(size_t)node * D + k0])
            : make_float4(0.f, 0.f, 0.f, 0.f);
        xsT[k0 + 0][o] = xv.x; xsT[k0 + 1][o] = xv.y;
        xsT[k0 + 2][o] = xv.z; xsT[k0 + 3][o] = xv.w;
    }
    __syncthreads();

    int nn = (t >> 4) * 4;     // node group
    int fo = (t & 15) * 4;     // feat group
    float4 bv = *reinterpret_cast<const float4*>(&b[fo]);
    float a[4][4];
#pragma unroll
    for (int ni = 0; ni < 4; ++ni) {
        a[ni][0] = bv.x; a[ni][1] = bv.y; a[ni][2] = bv.z; a[ni][3] = bv.w;
    }
#pragma unroll 8
    for (int k = 0; k < D; ++k) {
        float4 xv = *reinterpret_cast<const float4*>(&xsT[k][nn]);
        float4 wv = *reinterpret_cast<const float4*>(&WsT[k][fo]);
        a[0][0] = fmaf(xv.x, wv.x, a[0][0]); a[0][1] = fmaf(xv.x, wv.y, a[0][1]);
        a[0][2] = fmaf(xv.x, wv.z, a[0][2]); a[0][3] = fmaf(xv.x, wv.w, a[0][3]);
        a[1][0] = fmaf(xv.y, wv.x, a[1][0]); a[1][1] = fmaf(xv.y, wv.y, a[1][1]);
        a[1][2] = fmaf(xv.y, wv.z, a[1][2]); a[1][3] = fmaf(xv.y, wv.w, a[1][3]);
        a[2][0] = fmaf(xv.z, wv.x, a[2][0]); a[2][1] = fmaf(xv.z, wv.y, a[2][1]);
        a[2][2] = fmaf(xv.z, wv.z, a[2][2]); a[2][3] = fmaf(xv.z, wv.w, a[2][3]);
        a[3][0] = fmaf(xv.w, wv.x, a[3][0]); a[3][1] = fmaf(xv.w, wv.y, a[3][1]);
        a[3][2] = fmaf(xv.w, wv.z, a[3][2]); a[3][3] = fmaf(xv.w, wv.w, a[3][3]);
    }
#pragma unroll
    for (int ni = 0; ni < 4; ++ni) {
        int node = base + nn + ni;
        if (node < N_NODES) {
            ushort4 hv;
            hv.x = f2bf(a[ni][0]); hv.y = f2bf(a[ni][1]);
            hv.z = f2bf(a[ni][2]); hv.w = f2bf(a[ni][3]);
            *reinterpret_cast<ushort4*>(&h[(size_t)node * D + fo]) = hv;
        }
    }
}

// ---------------------------------------------------------------------------
// Pass A1: per-(bin, block) edge counts via LDS histogram. NBINS=1563.
// ---------------------------------------------------------------------------
__global__ __launch_bounds__(256) void count_kernel(
    const int* __restrict__ dst, int* __restrict__ counts) {
    __shared__ int cnt[NBINS];
    int tid = threadIdx.x, blk = blockIdx.x;
    for (int i = tid; i < NBINS; i += 256) cnt[i] = 0;
    __syncthreads();
    int eend = min(N_EDGES, (blk + 1) * CHUNK);
    for (int e = blk * CHUNK + tid; e < eend; e += 256)
        atomicAdd(&cnt[dst[e] >> BIN_SHIFT], 1);
    __syncthreads();
    for (int i = tid; i < NBINS; i += 256)
        counts[i * NBLK_A + blk] = cnt[i];
}

// ---------------------------------------------------------------------------
// Pass A2: per-bin exclusive scan over the 256 block-counts (1 block/bin).
// ---------------------------------------------------------------------------
__global__ __launch_bounds__(256) void rowscan_kernel(
    int* __restrict__ counts, int* __restrict__ bintot) {
    __shared__ int s[256];
    int bin = blockIdx.x, tid = threadIdx.x;
    int c = counts[bin * NBLK_A + tid];
    s[tid] = c; __syncthreads();
    for (int off = 1; off < 256; off <<= 1) {
        int v = (tid >= off) ? s[tid - off] : 0;
        __syncthreads(); s[tid] += v; __syncthreads();
    }
    counts[bin * NBLK_A + tid] = s[tid] - c;   // exclusive
    if (tid == 255) bintot[bin] = s[255];
}

// ---------------------------------------------------------------------------
// Pass A2b: exclusive scan over 1563 bin totals (512 thr x 4 items).
// ---------------------------------------------------------------------------
__global__ __launch_bounds__(512) void basescan_kernel(
    const int* __restrict__ bintot, int* __restrict__ binbase) {
    __shared__ int s[512];
    int tid = threadIdx.x;
    int c[4]; int tot = 0;
#pragma unroll
    for (int j = 0; j < 4; ++j) {
        int idx = tid * 4 + j;
        c[j] = (idx < NBINS) ? bintot[idx] : 0;
        tot += c[j];
    }
    s[tid] = tot; __syncthreads();
    for (int off = 1; off < 512; off <<= 1) {
        int v = (tid >= off) ? s[tid - off] : 0;
        __syncthreads(); s[tid] += v; __syncthreads();
    }
    int run = s[tid] - tot;   // exclusive base for this thread's 4 items
#pragma unroll
    for (int j = 0; j < 4; ++j) {
        int idx = tid * 4 + j;
        if (idx < NBINS) binbase[idx] = run;
        run += c[j];
    }
    if (tid == (NBINS - 1) / 4) binbase[NBINS] = run;  // == N_EDGES
}

// ---------------------------------------------------------------------------
// Pass A3: write edges into per-(bin, block) private CSR regions.
// ---------------------------------------------------------------------------
__global__ __launch_bounds__(256) void binfill_kernel(
    const int* __restrict__ src, const int* __restrict__ dst,
    const float* __restrict__ w, const int* __restrict__ counts,
    const int* __restrict__ binbase, int2* __restrict__ csr) {
    __shared__ int cur[NBINS];
    int tid = threadIdx.x, blk = blockIdx.x;
    for (int i = tid; i < NBINS; i += 256)
        cur[i] = binbase[i] + counts[i * NBLK_A + blk];
    __syncthreads();
    int eend = min(N_EDGES, (blk + 1) * CHUNK);
    for (int e = blk * CHUNK + tid; e < eend; e += 256) {
        int d = dst[e];
        int bin = d >> BIN_SHIFT;
        int slot = atomicAdd(&cur[bin], 1);
        csr[slot] = make_int2(src[e] | ((d & (NODES_PER_BIN - 1)) << 17),
                              __float_as_int(w[e]));
    }
}

// ---------------------------------------------------------------------------
// Pass B: one block per 64-node bin (grid 1563). No filter, no redundant
// scan: 4 waves split the bin's edge range. Branchless 8-edge batches:
// 8 csr loads -> 8 h-row gathers -> 8 LDS atomics, all independent within
// a stage -> 8x memory-level parallelism per wave (the Round-8/10 kernel
// exposed full latency per ~1 useful edge; this is the fix).
// ---------------------------------------------------------------------------
__global__ __launch_bounds__(256) void binacc_kernel(
    const unsigned short* __restrict__ h, const int* __restrict__ binbase,
    const int2* __restrict__ csr, float* __restrict__ out) {
    __shared__ float acc[NODES_PER_BIN * D];   // 16 KB
    int tid = threadIdx.x;
    int bin = blockIdx.x;
    float4* a4 = reinterpret_cast<float4*>(acc);
#pragma unroll
    for (int i = tid; i < NODES_PER_BIN * D / 4; i += 256)
        a4[i] = make_float4(0.f, 0.f, 0.f, 0.f);
    __syncthreads();

    int lane = tid & 63, wid = tid >> 6;
    int start = binbase[bin], endv = binbase[bin + 1];
    int cnt = endv - start;
    int per = (cnt + 3) >> 2;
    int i = start + wid * per;
    int iend = min(i + per, endv);

    for (; i + 8 <= iend; i += 8) {
        int2 p0 = csr[i+0], p1 = csr[i+1], p2 = csr[i+2], p3 = csr[i+3];
        int2 p4 = csr[i+4], p5 = csr[i+5], p6 = csr[i+6], p7 = csr[i+7];
        float h0 = bf2f(h[(size_t)(p0.x & 0x1FFFF) * D + lane]);
        float h1 = bf2f(h[(size_t)(p1.x & 0x1FFFF) * D + lane]);
        float h2 = bf2f(h[(size_t)(p2.x & 0x1FFFF) * D + lane]);
        float h3 = bf2f(h[(size_t)(p3.x & 0x1FFFF) * D + lane]);
        float h4 = bf2f(h[(size_t)(p4.x & 0x1FFFF) * D + lane]);
        float h5 = bf2f(h[(size_t)(p5.x & 0x1FFFF) * D + lane]);
        float h6 = bf2f(h[(size_t)(p6.x & 0x1FFFF) * D + lane]);
        float h7 = bf2f(h[(size_t)(p7.x & 0x1FFFF) * D + lane]);
        atomicAdd(&acc[((p0.x >> 17) & 63) * D + lane], h0 * __int_as_float(p0.y));
        atomicAdd(&acc[((p1.x >> 17) & 63) * D + lane], h1 * __int_as_float(p1.y));
        atomicAdd(&acc[((p2.x >> 17) & 63) * D + lane], h2 * __int_as_float(p2.y));
        atomicAdd(&acc[((p3.x >> 17) & 63) * D + lane], h3 * __int_as_float(p3.y));
        atomicAdd(&acc[((p4.x >> 17) & 63) * D + lane], h4 * __int_as_float(p4.y));
        atomicAdd(&acc[((p5.x >> 17) & 63) * D + lane], h5 * __int_as_float(p5.y));
        atomicAdd(&acc[((p6.x >> 17) & 63) * D + lane], h6 * __int_as_float(p6.y));
        atomicAdd(&acc[((p7.x >> 17) & 63) * D + lane], h7 * __int_as_float(p7.y));
    }
    for (; i < iend; ++i) {
        int2 p = csr[i];
        float hv = bf2f(h[(size_t)(p.x & 0x1FFFF) * D + lane]);
        atomicAdd(&acc[((p.x >> 17) & 63) * D + lane], hv * __int_as_float(p.y));
    }
    __syncthreads();

    int node0 = bin << BIN_SHIFT;
    int lim = min(NODES_PER_BIN, N_NODES - node0);
    float4* o4 = reinterpret_cast<float4*>(out + (size_t)node0 * D);
    for (int k = tid; k < lim * (D / 4); k += 256) o4[k] = a4[k];
}

extern "C" void kernel_launch(void* const* d_in, const int* in_sizes, int n_in,
                              void* d_out, int out_size, void* d_ws, size_t ws_size,
                              hipStream_t stream) {
    const float* x   = (const float*)d_in[0];
    const int*   src = (const int*)d_in[1];
    const int*   dst = (const int*)d_in[2];
    const float* w   = (const float*)d_in[3];
    const float* W   = (const float*)d_in[4];
    const float* b   = (const float*)d_in[5];
    float*       out = (float*)d_out;

    char* ws = (char*)d_ws;
    unsigned short* h       = (unsigned short*)(ws + OFF_H);
    int2*           csr     = (int2*)(ws + OFF_CSR);
    int*            counts  = (int*)(ws + OFF_CNT);
    int*            bintot  = (int*)(ws + OFF_TOT);
    int*            binbase = (int*)(ws + OFF_BASE);

    linear_kernel  <<<(N_NODES + 63) / 64, 256, 0, stream>>>(x, W, b, h);
    count_kernel   <<<NBLK_A, 256, 0, stream>>>(dst, counts);
    rowscan_kernel <<<NBINS, 256, 0, stream>>>(counts, bintot);
    basescan_kernel<<<1, 512, 0, stream>>>(bintot, binbase);
    binfill_kernel <<<NBLK_A, 256, 0, stream>>>(src, dst, w, counts, binbase, csr);
    binacc_kernel  <<<NBINS, 256, 0, stream>>>(h, binbase, csr, out);
}

// Round 16
// 188.368 us; speedup vs baseline: 3.6589x; 3.1707x over previous
//
#include <hip/hip_runtime.h>

#define N_NODES 100000
#define N_EDGES 1200000
#define D 64

#define BIN_SHIFT 6
#define NODES_PER_BIN 64
#define NBINS ((N_NODES + NODES_PER_BIN - 1) / NODES_PER_BIN)   // 1563
#define NBLK_A 256
#define CHUNK ((N_EDGES + NBLK_A - 1) / NBLK_A)                 // 4688
#define BIN_CAP 1536   // mean 768, sigma ~28 -> 27 sigma headroom

// ---- workspace layout (bytes), total ~24.4 MB ----
#define OFF_H    0u          // ushort[N_NODES*D]   12.8 MB (h in bf16)
#define OFF_CSR  12800000u   // int2[N_EDGES]        9.6 MB {src|dlow<<17, w_bits}
#define OFF_CNT  22400000u   // int[NBINS*NBLK_A]    1.6 MB counts->offs
#define OFF_TOT  24000512u   // int[NBINS]
#define OFF_BASE 24006768u   // int[NBINS+1]
#define OFF_RP   24013056u   // int[N_NODES+1]       400 KB per-node rowptr

__device__ __forceinline__ unsigned short f2bf(float f) {
    unsigned u = __float_as_uint(f);
    return (unsigned short)((u + 0x7FFFu + ((u >> 16) & 1u)) >> 16);  // RNE
}
__device__ __forceinline__ float bf2f(unsigned short s) {
    return __uint_as_float(((unsigned)s) << 16);
}

// ---------------------------------------------------------------------------
// h = bf16(x @ W^T + b), tiled: block = 64 nodes x 64 feats, 256 threads,
// 4x4 register tile each; x/W staged transposed in padded LDS.
// ---------------------------------------------------------------------------
__global__ __launch_bounds__(256) void linear_kernel(
    const float* __restrict__ x, const float* __restrict__ W,
    const float* __restrict__ b, unsigned short* __restrict__ h) {
    __shared__ float xsT[D][68];  // xsT[k][node]
    __shared__ float WsT[D][68];  // WsT[k][feat]
    int t = threadIdx.x;
    int base = blockIdx.x * 64;
    int rr = t >> 4;           // 0..15
    int k0 = (t & 15) * 4;     // 0..60
#pragma unroll
    for (int p = 0; p < 4; ++p) {
        int o = rr + p * 16;
        float4 wv = *reinterpret_cast<const float4*>(&W[o * D + k0]);
        WsT[k0 + 0][o] = wv.x; WsT[k0 + 1][o] = wv.y;
        WsT[k0 + 2][o] = wv.z; WsT[k0 + 3][o] = wv.w;
        int node = base + o;
        float4 xv = (node < N_NODES)
            ? *reinterpret_cast<const float4*>(&x[(size_t)node * D + k0])
            : make_float4(0.f, 0.f, 0.f, 0.f);
        xsT[k0 + 0][o] = xv.x; xsT[k0 + 1][o] = xv.y;
        xsT[k0 + 2][o] = xv.z; xsT[k0 + 3][o] = xv.w;
    }
    __syncthreads();

    int nn = (t >> 4) * 4;     // node group
    int fo = (t & 15) * 4;     // feat group
    float4 bv = *reinterpret_cast<const float4*>(&b[fo]);
    float a[4][4];
#pragma unroll
    for (int ni = 0; ni < 4; ++ni) {
        a[ni][0] = bv.x; a[ni][1] = bv.y; a[ni][2] = bv.z; a[ni][3] = bv.w;
    }
#pragma unroll 8
    for (int k = 0; k < D; ++k) {
        float4 xv = *reinterpret_cast<const float4*>(&xsT[k][nn]);
        float4 wv = *reinterpret_cast<const float4*>(&WsT[k][fo]);
        a[0][0] = fmaf(xv.x, wv.x, a[0][0]); a[0][1] = fmaf(xv.x, wv.y, a[0][1]);
        a[0][2] = fmaf(xv.x, wv.z, a[0][2]); a[0][3] = fmaf(xv.x, wv.w, a[0][3]);
        a[1][0] = fmaf(xv.y, wv.x, a[1][0]); a[1][1] = fmaf(xv.y, wv.y, a[1][1]);
        a[1][2] = fmaf(xv.y, wv.z, a[1][2]); a[1][3] = fmaf(xv.y, wv.w, a[1][3]);
        a[2][0] = fmaf(xv.z, wv.x, a[2][0]); a[2][1] = fmaf(xv.z, wv.y, a[2][1]);
        a[2][2] = fmaf(xv.z, wv.z, a[2][2]); a[2][3] = fmaf(xv.z, wv.w, a[2][3]);
        a[3][0] = fmaf(xv.w, wv.x, a[3][0]); a[3][1] = fmaf(xv.w, wv.y, a[3][1]);
        a[3][2] = fmaf(xv.w, wv.z, a[3][2]); a[3][3] = fmaf(xv.w, wv.w, a[3][3]);
    }
#pragma unroll
    for (int ni = 0; ni < 4; ++ni) {
        int node = base + nn + ni;
        if (node < N_NODES) {
            ushort4 hv;
            hv.x = f2bf(a[ni][0]); hv.y = f2bf(a[ni][1]);
            hv.z = f2bf(a[ni][2]); hv.w = f2bf(a[ni][3]);
            *reinterpret_cast<ushort4*>(&h[(size_t)node * D + fo]) = hv;
        }
    }
}

// ---------------------------------------------------------------------------
// Pass A1: per-(bin, block) edge counts via LDS histogram. NBINS=1563.
// ---------------------------------------------------------------------------
__global__ __launch_bounds__(256) void count_kernel(
    const int* __restrict__ dst, int* __restrict__ counts) {
    __shared__ int cnt[NBINS];
    int tid = threadIdx.x, blk = blockIdx.x;
    for (int i = tid; i < NBINS; i += 256) cnt[i] = 0;
    __syncthreads();
    int eend = min(N_EDGES, (blk + 1) * CHUNK);
    for (int e = blk * CHUNK + tid; e < eend; e += 256)
        atomicAdd(&cnt[dst[e] >> BIN_SHIFT], 1);
    __syncthreads();
    for (int i = tid; i < NBINS; i += 256)
        counts[i * NBLK_A + blk] = cnt[i];
}

// ---------------------------------------------------------------------------
// Pass A2: per-bin exclusive scan over the 256 block-counts (1 block/bin).
// ---------------------------------------------------------------------------
__global__ __launch_bounds__(256) void rowscan_kernel(
    int* __restrict__ counts, int* __restrict__ bintot) {
    __shared__ int s[256];
    int bin = blockIdx.x, tid = threadIdx.x;
    int c = counts[bin * NBLK_A + tid];
    s[tid] = c; __syncthreads();
    for (int off = 1; off < 256; off <<= 1) {
        int v = (tid >= off) ? s[tid - off] : 0;
        __syncthreads(); s[tid] += v; __syncthreads();
    }
    counts[bin * NBLK_A + tid] = s[tid] - c;   // exclusive
    if (tid == 255) bintot[bin] = s[255];
}

// ---------------------------------------------------------------------------
// Pass A2b: exclusive scan over 1563 bin totals (512 thr x 4 items).
// ---------------------------------------------------------------------------
__global__ __launch_bounds__(512) void basescan_kernel(
    const int* __restrict__ bintot, int* __restrict__ binbase) {
    __shared__ int s[512];
    int tid = threadIdx.x;
    int c[4]; int tot = 0;
#pragma unroll
    for (int j = 0; j < 4; ++j) {
        int idx = tid * 4 + j;
        c[j] = (idx < NBINS) ? bintot[idx] : 0;
        tot += c[j];
    }
    s[tid] = tot; __syncthreads();
    for (int off = 1; off < 512; off <<= 1) {
        int v = (tid >= off) ? s[tid - off] : 0;
        __syncthreads(); s[tid] += v; __syncthreads();
    }
    int run = s[tid] - tot;   // exclusive base for this thread's 4 items
#pragma unroll
    for (int j = 0; j < 4; ++j) {
        int idx = tid * 4 + j;
        if (idx < NBINS) binbase[idx] = run;
        run += c[j];
    }
    if (tid == (NBINS - 1) / 4) binbase[NBINS] = run;  // == N_EDGES
}

// ---------------------------------------------------------------------------
// Pass A3: write edges into per-(bin, block) private CSR regions.
// ---------------------------------------------------------------------------
__global__ __launch_bounds__(256) void binfill_kernel(
    const int* __restrict__ src, const int* __restrict__ dst,
    const float* __restrict__ w, const int* __restrict__ counts,
    const int* __restrict__ binbase, int2* __restrict__ csr) {
    __shared__ int cur[NBINS];
    int tid = threadIdx.x, blk = blockIdx.x;
    for (int i = tid; i < NBINS; i += 256)
        cur[i] = binbase[i] + counts[i * NBLK_A + blk];
    __syncthreads();
    int eend = min(N_EDGES, (blk + 1) * CHUNK);
    for (int e = blk * CHUNK + tid; e < eend; e += 256) {
        int d = dst[e];
        int bin = d >> BIN_SHIFT;
        int slot = atomicAdd(&cur[bin], 1);
        csr[slot] = make_int2(src[e] | ((d & (NODES_PER_BIN - 1)) << 17),
                              __float_as_int(w[e]));
    }
}

// ---------------------------------------------------------------------------
// Pass A4: per-bin counting sort by dst-low (one block per bin).
// Two sequential reads of the bin's csr range (2nd is L2-hot), LDS scatter,
// sequential write-back -> csr becomes fully dst-sorted. Also emits the
// per-node rowptr (start + exclusive prefix of the 64 in-bin degrees).
// ---------------------------------------------------------------------------
__global__ __launch_bounds__(256) void sortbin_kernel(
    int2* __restrict__ csr, const int* __restrict__ binbase,
    int* __restrict__ rowptr) {
    __shared__ int2 sbuf[BIN_CAP];          // 12 KB
    __shared__ int dcnt[NODES_PER_BIN];
    __shared__ int dinc[NODES_PER_BIN];
    __shared__ int cursor[NODES_PER_BIN];
    int tid = threadIdx.x, bin = blockIdx.x;
    int start = binbase[bin], endv = binbase[bin + 1];
    int n = min(endv - start, BIN_CAP);
    if (tid < NODES_PER_BIN) dcnt[tid] = 0;
    __syncthreads();
    // pass 1: count per-dst-low degrees
    for (int k = tid; k < n; k += 256) {
        int2 p = csr[start + k];
        atomicAdd(&dcnt[(p.x >> 17) & 63], 1);
    }
    __syncthreads();
    // inclusive Hillis-Steele over 64 counters (first 64 threads)
    if (tid < 64) dinc[tid] = dcnt[tid];
    __syncthreads();
    for (int off = 1; off < 64; off <<= 1) {
        int v = 0;
        if (tid < 64 && tid >= off) v = dinc[tid - off];
        __syncthreads();
        if (tid < 64) dinc[tid] += v;
        __syncthreads();
    }
    if (tid < 64) {
        int excl = dinc[tid] - dcnt[tid];
        cursor[tid] = excl;
        int node = (bin << BIN_SHIFT) + tid;
        if (node < N_NODES) rowptr[node] = start + excl;
    }
    if (bin == NBINS - 1 && tid == 0) rowptr[N_NODES] = N_EDGES;
    __syncthreads();
    // pass 2: scatter into sorted order in LDS
    for (int k = tid; k < n; k += 256) {
        int2 p = csr[start + k];
        int slot = atomicAdd(&cursor[(p.x >> 17) & 63], 1);
        sbuf[slot] = p;
    }
    __syncthreads();
    // sequential write-back (full lines)
    for (int k = tid; k < n; k += 256) csr[start + k] = sbuf[k];
}

// ---------------------------------------------------------------------------
// Pass B: per-node gather with REGISTER accumulation (the structure that
// measured <=87us in Round 3; LDS-atomic binacc variants measured 449-518us).
// One wave per dst node, lane = feature; 8/4/1-tier edge batching so up to
// 8 independent h-row gathers are in flight.
// ---------------------------------------------------------------------------
__global__ __launch_bounds__(256) void gather_kernel(
    const unsigned short* __restrict__ h, const int* __restrict__ rowptr,
    const int2* __restrict__ csr, float* __restrict__ out) {
    int lane = threadIdx.x & 63;
    int node = blockIdx.x * 4 + (threadIdx.x >> 6);
    if (node >= N_NODES) return;
    int i = rowptr[node], endv = rowptr[node + 1];
    float acc = 0.0f;
    for (; i + 8 <= endv; i += 8) {
        int2 p0 = csr[i+0], p1 = csr[i+1], p2 = csr[i+2], p3 = csr[i+3];
        int2 p4 = csr[i+4], p5 = csr[i+5], p6 = csr[i+6], p7 = csr[i+7];
        float h0 = bf2f(h[(size_t)(p0.x & 0x1FFFF) * D + lane]);
        float h1 = bf2f(h[(size_t)(p1.x & 0x1FFFF) * D + lane]);
        float h2 = bf2f(h[(size_t)(p2.x & 0x1FFFF) * D + lane]);
        float h3 = bf2f(h[(size_t)(p3.x & 0x1FFFF) * D + lane]);
        float h4 = bf2f(h[(size_t)(p4.x & 0x1FFFF) * D + lane]);
        float h5 = bf2f(h[(size_t)(p5.x & 0x1FFFF) * D + lane]);
        float h6 = bf2f(h[(size_t)(p6.x & 0x1FFFF) * D + lane]);
        float h7 = bf2f(h[(size_t)(p7.x & 0x1FFFF) * D + lane]);
        acc = fmaf(h0, __int_as_float(p0.y), acc);
        acc = fmaf(h1, __int_as_float(p1.y), acc);
        acc = fmaf(h2, __int_as_float(p2.y), acc);
        acc = fmaf(h3, __int_as_float(p3.y), acc);
        acc = fmaf(h4, __int_as_float(p4.y), acc);
        acc = fmaf(h5, __int_as_float(p5.y), acc);
        acc = fmaf(h6, __int_as_float(p6.y), acc);
        acc = fmaf(h7, __int_as_float(p7.y), acc);
    }
    if (i + 4 <= endv) {
        int2 p0 = csr[i+0], p1 = csr[i+1], p2 = csr[i+2], p3 = csr[i+3];
        float h0 = bf2f(h[(size_t)(p0.x & 0x1FFFF) * D + lane]);
        float h1 = bf2f(h[(size_t)(p1.x & 0x1FFFF) * D + lane]);
        float h2 = bf2f(h[(size_t)(p2.x & 0x1FFFF) * D + lane]);
        float h3 = bf2f(h[(size_t)(p3.x & 0x1FFFF) * D + lane]);
        acc = fmaf(h0, __int_as_float(p0.y), acc);
        acc = fmaf(h1, __int_as_float(p1.y), acc);
        acc = fmaf(h2, __int_as_float(p2.y), acc);
        acc = fmaf(h3, __int_as_float(p3.y), acc);
        i += 4;
    }
    for (; i < endv; ++i) {
        int2 p = csr[i];
        acc = fmaf(bf2f(h[(size_t)(p.x & 0x1FFFF) * D + lane]),
                   __int_as_float(p.y), acc);
    }
    out[(size_t)node * D + lane] = acc;   // covers all nodes -> no memset
}

extern "C" void kernel_launch(void* const* d_in, const int* in_sizes, int n_in,
                              void* d_out, int out_size, void* d_ws, size_t ws_size,
                              hipStream_t stream) {
    const float* x   = (const float*)d_in[0];
    const int*   src = (const int*)d_in[1];
    const int*   dst = (const int*)d_in[2];
    const float* w   = (const float*)d_in[3];
    const float* W   = (const float*)d_in[4];
    const float* b   = (const float*)d_in[5];
    float*       out = (float*)d_out;

    char* ws = (char*)d_ws;
    unsigned short* h       = (unsigned short*)(ws + OFF_H);
    int2*           csr     = (int2*)(ws + OFF_CSR);
    int*            counts  = (int*)(ws + OFF_CNT);
    int*            bintot  = (int*)(ws + OFF_TOT);
    int*            binbase = (int*)(ws + OFF_BASE);
    int*            rowptr  = (int*)(ws + OFF_RP);

    linear_kernel  <<<(N_NODES + 63) / 64, 256, 0, stream>>>(x, W, b, h);
    count_kernel   <<<NBLK_A, 256, 0, stream>>>(dst, counts);
    rowscan_kernel <<<NBINS, 256, 0, stream>>>(counts, bintot);
    basescan_kernel<<<1, 512, 0, stream>>>(bintot, binbase);
    binfill_kernel <<<NBLK_A, 256, 0, stream>>>(src, dst, w, counts, binbase, csr);
    sortbin_kernel <<<NBINS, 256, 0, stream>>>(csr, binbase, rowptr);
    gather_kernel  <<<(N_NODES + 3) / 4, 256, 0, stream>>>(h, rowptr, csr, out);
}